// Round 8
// baseline (125.286 us; speedup 1.0000x reference)
//
#include <hip/hip_runtime.h>
#include <hip/hip_bf16.h>

#define B_ 2
#define L_ 4096
#define DIM_ 512
#define HEADS_ 8
#define HDIM_ 64
#define KS_ 33
#define QKS_ 1024   // qk buffer row stride (Q cols 0-511, K cols 512-1023)

typedef __bf16 bf16;
typedef __bf16 bf16x4 __attribute__((ext_vector_type(4)));
typedef __bf16 bf16x8 __attribute__((ext_vector_type(8)));
typedef float f32x4 __attribute__((ext_vector_type(4)));

typedef __attribute__((address_space(3))) void lds_void;
typedef __attribute__((address_space(1))) const void glb_void;

__device__ __forceinline__ void async_cp16(const bf16* g, bf16* l)
{
    __builtin_amdgcn_global_load_lds((glb_void*)g, (lds_void*)l, 16, 0, 0);
}

// ---------------------------------------------------------------------------
// Single fused fp32->bf16 convert for all 5 inputs (R5, passing, unchanged).
// ---------------------------------------------------------------------------
__global__ __launch_bounds__(256)
void cvt_all(const float* __restrict__ x,  const float* __restrict__ wq,
             const float* __restrict__ bq, const float* __restrict__ wp,
             const float* __restrict__ bp,
             bf16* __restrict__ xb,  bf16* __restrict__ wqb,
             bf16* __restrict__ bqb, bf16* __restrict__ wpb,
             bf16* __restrict__ bpb)
{
    const int blk = blockIdx.x;
    const float* src; bf16* dst; int n, base;
    if (blk < 2048)       { src = x;  dst = xb;  n = 4194304; base = blk; }
    else if (blk < 2432)  { src = wq; dst = wqb; n = 786432;  base = blk - 2048; }
    else if (blk < 2560)  { src = wp; dst = wpb; n = 262144;  base = blk - 2432; }
    else if (blk == 2560) { src = bq; dst = bqb; n = 1536;    base = 0; }
    else                  { src = bp; dst = bpb; n = 512;     base = 0; }
    int i = base * 2048 + threadIdx.x * 8;
    if (i + 8 <= n) {
        float4 a = *(const float4*)(src + i);
        float4 b = *(const float4*)(src + i + 4);
        bf16x8 o;
        o[0] = (bf16)a.x; o[1] = (bf16)a.y; o[2] = (bf16)a.z; o[3] = (bf16)a.w;
        o[4] = (bf16)b.x; o[5] = (bf16)b.y; o[6] = (bf16)b.z; o[7] = (bf16)b.w;
        *(bf16x8*)(dst + i) = o;
    }
}

// ---------------------------------------------------------------------------
// QKV GEMM: C[8192,1536] = x @ w_qkv^T + b_qkv, but split outputs:
//   cols    0..1023 (Q,K) -> qk[row][col]            (stride 1024)
//   cols 1024..1535 (V)   -> vT[b][h][d][l]  TRANSPOSED (d-major), packed
//     bf16x4 stores: C-frag reg r holds 4 consecutive rows (= keys) ->
//     contiguous in vT. This kills the V transpose in attention.
// Main loop = R5's proven global_load_lds + XOR-swizzle structure.
// ---------------------------------------------------------------------------
__global__ __launch_bounds__(256)
void gemm_qkv(const bf16* __restrict__ A, const bf16* __restrict__ W,
              const bf16* __restrict__ bias,
              bf16* __restrict__ qk, bf16* __restrict__ vT)
{
    __shared__ bf16 As[128][64];
    __shared__ bf16 Bs[128][64];

    const int tid  = threadIdx.x;
    const int wave = tid >> 6;
    const int lane = tid & 63;
    const int wm   = (wave >> 1) * 64;
    const int wn   = (wave & 1) * 64;
    const int l16  = lane & 15;
    const int quad = lane >> 4;

    const int row0 = blockIdx.x * 128;
    const int col0 = blockIdx.y * 128;
    const int K    = DIM_;               // 512

    f32x4 acc[4][4] = {};

    for (int k0 = 0; k0 < K; k0 += 64) {
        #pragma unroll
        for (int it = 0; it < 4; ++it) {
            int f   = it * 256 + tid;
            int r   = f >> 3;
            int c8l = (f & 7) ^ (r & 7);
            async_cp16(&A[(size_t)(row0 + r) * K + k0 + c8l * 8], &As[r][(f & 7) * 8]);
            async_cp16(&W[(size_t)(col0 + r) * K + k0 + c8l * 8], &Bs[r][(f & 7) * 8]);
        }
        __syncthreads();

        #pragma unroll
        for (int ks = 0; ks < 2; ++ks) {
            bf16x8 af[4], bfr[4];
            #pragma unroll
            for (int i = 0; i < 4; ++i) {
                int ra = wm + i * 16 + l16;
                int rb = wn + i * 16 + l16;
                af[i]  = *(const bf16x8*)(&As[ra][((ks * 4 + quad) ^ (ra & 7)) * 8]);
                bfr[i] = *(const bf16x8*)(&Bs[rb][((ks * 4 + quad) ^ (rb & 7)) * 8]);
            }
            #pragma unroll
            for (int mi = 0; mi < 4; ++mi)
                #pragma unroll
                for (int ni = 0; ni < 4; ++ni)
                    acc[mi][ni] = __builtin_amdgcn_mfma_f32_16x16x32_bf16(
                        af[mi], bfr[ni], acc[mi][ni], 0, 0, 0);
        }
        __syncthreads();
    }

    if (col0 < 1024) {
        // Q,K part: row-major into qk (stride 1024)
        #pragma unroll
        for (int ni = 0; ni < 4; ++ni) {
            int n = col0 + wn + ni * 16 + l16;
            float bv = (float)bias[n];
            #pragma unroll
            for (int mi = 0; mi < 4; ++mi) {
                int mrow = row0 + wm + mi * 16 + quad * 4;
                #pragma unroll
                for (int r = 0; r < 4; ++r)
                    qk[(size_t)(mrow + r) * QKS_ + n] = (bf16)(acc[mi][ni][r] + bv);
            }
        }
    } else {
        // V part: transposed into vT[b][h][d][l], 4 keys packed per store
        #pragma unroll
        for (int ni = 0; ni < 4; ++ni) {
            int nf = col0 + wn + ni * 16 + l16;     // 1024..1535
            float bv = (float)bias[nf];
            int hd = nf - 1024;                     // h*64 + d
            #pragma unroll
            for (int mi = 0; mi < 4; ++mi) {
                int m = row0 + wm + mi * 16 + quad * 4;
                int b = m >> 12;
                int l = m & (L_ - 1);
                bf16x4 v4;
                #pragma unroll
                for (int r = 0; r < 4; ++r) v4[r] = (bf16)(acc[mi][ni][r] + bv);
                *(bf16x4*)(vT + ((size_t)(b * DIM_ + hd)) * L_ + l) = v4;
            }
        }
    }
}

// ---------------------------------------------------------------------------
// C[M,N] = A[M,K] * W[N,K]^T + bias[N] (R5, passing, unchanged) — proj GEMM.
// ---------------------------------------------------------------------------
template <typename OutT>
__global__ __launch_bounds__(256)
void gemm_nt_bias(const bf16* __restrict__ A, const bf16* __restrict__ W,
                  const bf16* __restrict__ bias, OutT* __restrict__ C,
                  int M, int N, int K)
{
    __shared__ bf16 As[128][64];
    __shared__ bf16 Bs[128][64];

    const int tid  = threadIdx.x;
    const int wave = tid >> 6;
    const int lane = tid & 63;
    const int wm   = (wave >> 1) * 64;
    const int wn   = (wave & 1) * 64;
    const int l16  = lane & 15;
    const int quad = lane >> 4;

    const int row0 = blockIdx.x * 128;
    const int col0 = blockIdx.y * 128;

    f32x4 acc[4][4] = {};

    for (int k0 = 0; k0 < K; k0 += 64) {
        #pragma unroll
        for (int it = 0; it < 4; ++it) {
            int f   = it * 256 + tid;
            int r   = f >> 3;
            int c8l = (f & 7) ^ (r & 7);
            async_cp16(&A[(size_t)(row0 + r) * K + k0 + c8l * 8], &As[r][(f & 7) * 8]);
            async_cp16(&W[(size_t)(col0 + r) * K + k0 + c8l * 8], &Bs[r][(f & 7) * 8]);
        }
        __syncthreads();

        #pragma unroll
        for (int ks = 0; ks < 2; ++ks) {
            bf16x8 af[4], bfr[4];
            #pragma unroll
            for (int i = 0; i < 4; ++i) {
                int ra = wm + i * 16 + l16;
                int rb = wn + i * 16 + l16;
                af[i]  = *(const bf16x8*)(&As[ra][((ks * 4 + quad) ^ (ra & 7)) * 8]);
                bfr[i] = *(const bf16x8*)(&Bs[rb][((ks * 4 + quad) ^ (rb & 7)) * 8]);
            }
            #pragma unroll
            for (int mi = 0; mi < 4; ++mi)
                #pragma unroll
                for (int ni = 0; ni < 4; ++ni)
                    acc[mi][ni] = __builtin_amdgcn_mfma_f32_16x16x32_bf16(
                        af[mi], bfr[ni], acc[mi][ni], 0, 0, 0);
        }
        __syncthreads();
    }

    #pragma unroll
    for (int ni = 0; ni < 4; ++ni) {
        int n = col0 + wn + ni * 16 + l16;
        float bv = (float)bias[n];
        #pragma unroll
        for (int mi = 0; mi < 4; ++mi) {
            int mrow = row0 + wm + mi * 16 + quad * 4;
            #pragma unroll
            for (int r = 0; r < 4; ++r)
                C[(size_t)(mrow + r) * N + n] = (OutT)(acc[mi][ni][r] + bv);
        }
    }
}

// ---------------------------------------------------------------------------
// MFMA neighborhood attention, vT version. One block = 64 queries of one
// (b,h); 4 waves x 16 queries. K staged via global_load_lds (XOR swizzle);
// Q direct; V-fragments are direct b128 loads from vT (d-major — no
// transpose anywhere). Per-wave k_base = clamp(q0w-16, 0, L-48) is 16-
// aligned; all 48 window keys are real rows (no clamp needed on frag 1);
// fully-masked chunks of frag 2 clamp to L-8 (finite data x P=0 = 0).
// Block->XCD decode matches gemm_qkv's writer XCD (panel % 8).
// ---------------------------------------------------------------------------
__global__ __launch_bounds__(256)
void na1d_attn_mfma(const bf16* __restrict__ qk, const bf16* __restrict__ vT,
                    bf16* __restrict__ att)
{
    __shared__ bf16 Klds[96 * 64];
    __shared__ bf16 Plds[4][16][72];

    const int tid  = threadIdx.x;
    const int wave = tid >> 6;
    const int lane = tid & 63;
    const int l16  = lane & 15;
    const int quad = lane >> 4;

    const int xcd  = blockIdx.x & 7;
    const int s    = blockIdx.x >> 3;
    const int jj   = s & 3;
    const int half = (s >> 2) & 1;
    const int h    = (s >> 3) & 7;
    const int b    = s >> 6;
    const int p    = jj * 8 + xcd;        // row panel 0..31
    const int Q0   = p * 128 + half * 64;

    const size_t rowbase = (size_t)b * L_;

    // ---- stage K: 96 rows x 8 chunks = 768 global_load_lds ----
    #pragma unroll
    for (int i = 0; i < 3; ++i) {
        int ck = i * 256 + tid;
        int r  = ck >> 3;
        int pc = ck & 7;
        int lc = pc ^ (r & 7);
        int g  = Q0 - 16 + r;
        g = g < 0 ? 0 : (g > L_ - 1 ? L_ - 1 : g);
        async_cp16(qk + (rowbase + g) * QKS_ + DIM_ + h * HDIM_ + lc * 8,
                   Klds + (size_t)ck * 8);
    }

    // ---- Q fragments (direct from global) ----
    const int q0w = Q0 + wave * 16;
    const bf16* qptr = qk + (rowbase + q0w + l16) * QKS_ + h * HDIM_ + quad * 8;
    bf16x8 qf0 = *(const bf16x8*)(qptr);
    bf16x8 qf1 = *(const bf16x8*)(qptr + 32);

    int k_base = q0w - 16;
    if (k_base > L_ - 48) k_base = L_ - 48;
    if (k_base < 0) k_base = 0;
    const int rel = k_base - (Q0 - 16);   // multiple of 16, in [0, 48]

    __syncthreads();                      // drains global_load_lds

    // ---- S = Q K^T over 3 key tiles (K from LDS) ----
    f32x4 sacc[3] = {};
    #pragma unroll
    for (int t = 0; t < 3; ++t) {
        int r = rel + t * 16 + l16;
        bf16x8 kf0 = *(const bf16x8*)(Klds + r * 64 + ((quad ^ (r & 7)) * 8));
        bf16x8 kf1 = *(const bf16x8*)(Klds + r * 64 + (((4 + quad) ^ (r & 7)) * 8));
        sacc[t] = __builtin_amdgcn_mfma_f32_16x16x32_bf16(qf0, kf0, sacc[t], 0, 0, 0);
        sacc[t] = __builtin_amdgcn_mfma_f32_16x16x32_bf16(qf1, kf1, sacc[t], 0, 0, 0);
    }

    // ---- mask + scale ----
    int offr[4];
    #pragma unroll
    for (int r = 0; r < 4; ++r) {
        int lq = q0w + quad * 4 + r;
        int st = lq - KS_ / 2;
        if (st < 0) st = 0;
        if (st > L_ - KS_) st = L_ - KS_;
        offr[r] = st - k_base;            // in [0,15]
    }
    float sv[3][4];
    #pragma unroll
    for (int t = 0; t < 3; ++t) {
        int j = t * 16 + l16;
        #pragma unroll
        for (int r = 0; r < 4; ++r) {
            float xv = sacc[t][r] * 0.125f;
            sv[t][r] = (j >= offr[r] && j <= offr[r] + 32) ? xv : -1e30f;
        }
    }

    // ---- softmax per row (quad-local butterfly over 16 lanes) ----
    float mr[4], sum[4];
    #pragma unroll
    for (int r = 0; r < 4; ++r)
        mr[r] = fmaxf(fmaxf(sv[0][r], sv[1][r]), sv[2][r]);
    #pragma unroll
    for (int o = 1; o < 16; o <<= 1)
        #pragma unroll
        for (int r = 0; r < 4; ++r)
            mr[r] = fmaxf(mr[r], __shfl_xor(mr[r], o, 64));
    #pragma unroll
    for (int t = 0; t < 3; ++t)
        #pragma unroll
        for (int r = 0; r < 4; ++r)
            sv[t][r] = __expf(sv[t][r] - mr[r]);
    #pragma unroll
    for (int r = 0; r < 4; ++r)
        sum[r] = sv[0][r] + sv[1][r] + sv[2][r];
    #pragma unroll
    for (int o = 1; o < 16; o <<= 1)
        #pragma unroll
        for (int r = 0; r < 4; ++r)
            sum[r] += __shfl_xor(sum[r], o, 64);
    #pragma unroll
    for (int r = 0; r < 4; ++r) {
        float inv = 1.0f / sum[r];
        #pragma unroll
        for (int t = 0; t < 3; ++t) sv[t][r] *= inv;
    }

    // ---- P -> LDS (C-layout write, A-layout read) ----
    bf16* P = &Plds[wave][0][0];
    {
        int rr = lane >> 2;
        int c0 = 48 + (lane & 3) * 4;
        *(bf16x4*)(&P[rr * 72 + c0]) = (bf16x4){(bf16)0.f, (bf16)0.f, (bf16)0.f, (bf16)0.f};
    }
    #pragma unroll
    for (int t = 0; t < 3; ++t)
        #pragma unroll
        for (int r = 0; r < 4; ++r)
            P[(quad * 4 + r) * 72 + t * 16 + l16] = (bf16)sv[t][r];
    __syncthreads();

    bf16x8 pf0 = *(const bf16x8*)(&P[l16 * 72 + quad * 8]);
    bf16x8 pf1 = *(const bf16x8*)(&P[l16 * 72 + 32 + quad * 8]);

    // ---- O = P V : V-fragments direct from vT (d-major) ----
    const bf16* vbase = vT + (size_t)(b * DIM_ + h * HDIM_) * L_;
    int c1 = k_base + quad * 8;           // frag-1 chunk start (always in-bounds)
    int c2 = k_base + 32 + quad * 8;      // frag-2 chunk start
    if (c2 > L_ - 8) c2 = L_ - 8;         // fully-masked chunks only; x P=0
    f32x4 o[4] = {};
    #pragma unroll
    for (int t = 0; t < 4; ++t) {
        const bf16* vrow = vbase + (size_t)(t * 16 + l16) * L_;
        bf16x8 vf0 = *(const bf16x8*)(vrow + c1);
        bf16x8 vf1 = *(const bf16x8*)(vrow + c2);
        o[t] = __builtin_amdgcn_mfma_f32_16x16x32_bf16(pf0, vf0, o[t], 0, 0, 0);
        o[t] = __builtin_amdgcn_mfma_f32_16x16x32_bf16(pf1, vf1, o[t], 0, 0, 0);
    }

    // ---- epilogue: C-layout col = d, row = query ----
    bf16* orow = att + (rowbase + q0w) * DIM_ + h * HDIM_;
    #pragma unroll
    for (int t = 0; t < 4; ++t)
        #pragma unroll
        for (int r = 0; r < 4; ++r)
            orow[(size_t)(quad * 4 + r) * DIM_ + t * 16 + l16] = (bf16)o[t][r];
}

extern "C" void kernel_launch(void* const* d_in, const int* in_sizes, int n_in,
                              void* d_out, int out_size, void* d_ws, size_t ws_size,
                              hipStream_t stream) {
    const int n_x  = B_ * L_ * DIM_;       // 4194304
    const int n_wq = 3 * DIM_ * DIM_;      // 786432
    const int n_bq = 3 * DIM_;             // 1536
    const int n_wp = DIM_ * DIM_;          // 262144
    const int n_bp = DIM_;                 // 512

    char* ws = (char*)d_ws;
    bf16* xb  = (bf16*)ws;
    bf16* wqb = xb  + n_x;
    bf16* bqb = wqb + n_wq;
    bf16* wpb = bqb + n_bq;
    bf16* bpb = wpb + n_wp;
    bf16* qk  = bpb + n_bp;                          // 8192 x 1024
    bf16* vT  = qk  + (size_t)8192 * 1024;           // 2 x 512 x 4096 (b, h*d, l)
    bf16* att = vT  + (size_t)B_ * DIM_ * L_;        // 8192 x 512

    float* out = (float*)d_out;
    const int M = B_ * L_;  // 8192

    cvt_all<<<2562, 256, 0, stream>>>(
        (const float*)d_in[0], (const float*)d_in[1], (const float*)d_in[2],
        (const float*)d_in[3], (const float*)d_in[4],
        xb, wqb, bqb, wpb, bpb);

    gemm_qkv<<<dim3(M / 128, (3 * DIM_) / 128), 256, 0, stream>>>(
        xb, wqb, bqb, qk, vT);

    na1d_attn_mfma<<<dim3((B_ * HEADS_ * L_) / 64), 256, 0, stream>>>(qk, vT, att);

    gemm_nt_bias<float><<<dim3(M / 128, DIM_ / 128), 256, 0, stream>>>(
        att, wpb, bpb, out, M, DIM_, DIM_);
}

// Round 9
// 118.016 us; speedup vs baseline: 1.0616x; 1.0616x over previous
//
#include <hip/hip_runtime.h>
#include <hip/hip_bf16.h>

#define B_ 2
#define L_ 4096
#define DIM_ 512
#define HEADS_ 8
#define HDIM_ 64
#define KS_ 33
#define QKS_ 1024   // qk buffer row stride (Q cols 0-511, K cols 512-1023)

typedef __bf16 bf16;
typedef __bf16 bf16x4 __attribute__((ext_vector_type(4)));
typedef __bf16 bf16x8 __attribute__((ext_vector_type(8)));
typedef float f32x4 __attribute__((ext_vector_type(4)));

typedef __attribute__((address_space(3))) void lds_void;
typedef __attribute__((address_space(1))) const void glb_void;

__device__ __forceinline__ void async_cp16(const bf16* g, bf16* l)
{
    __builtin_amdgcn_global_load_lds((glb_void*)g, (lds_void*)l, 16, 0, 0);
}

// ---------------------------------------------------------------------------
// Single fused fp32->bf16 convert for all 5 inputs (R5, passing, unchanged).
// ---------------------------------------------------------------------------
__global__ __launch_bounds__(256)
void cvt_all(const float* __restrict__ x,  const float* __restrict__ wq,
             const float* __restrict__ bq, const float* __restrict__ wp,
             const float* __restrict__ bp,
             bf16* __restrict__ xb,  bf16* __restrict__ wqb,
             bf16* __restrict__ bqb, bf16* __restrict__ wpb,
             bf16* __restrict__ bpb)
{
    const int blk = blockIdx.x;
    const float* src; bf16* dst; int n, base;
    if (blk < 2048)       { src = x;  dst = xb;  n = 4194304; base = blk; }
    else if (blk < 2432)  { src = wq; dst = wqb; n = 786432;  base = blk - 2048; }
    else if (blk < 2560)  { src = wp; dst = wpb; n = 262144;  base = blk - 2432; }
    else if (blk == 2560) { src = bq; dst = bqb; n = 1536;    base = 0; }
    else                  { src = bp; dst = bpb; n = 512;     base = 0; }
    int i = base * 2048 + threadIdx.x * 8;
    if (i + 8 <= n) {
        float4 a = *(const float4*)(src + i);
        float4 b = *(const float4*)(src + i + 4);
        bf16x8 o;
        o[0] = (bf16)a.x; o[1] = (bf16)a.y; o[2] = (bf16)a.z; o[3] = (bf16)a.w;
        o[4] = (bf16)b.x; o[5] = (bf16)b.y; o[6] = (bf16)b.z; o[7] = (bf16)b.w;
        *(bf16x8*)(dst + i) = o;
    }
}

// ---------------------------------------------------------------------------
// GEMM core, tile 128(M) x 64(N), BK=64, 256 threads. Per-wave 64x32:
// acc[4][2]. Staging = R5's proven global_load_lds + XOR swizzle; A-tile
// 1024 chunks + B-tile 512 chunks = 6 per thread. Rationale: N-tile 64
// doubles/sextuples blocks/CU (gemm_qkv 1536 blks = 6/CU, proj 512 = 2/CU)
// so barrier drains overlap across co-resident blocks (m114 mechanism) —
// the short-K (8 iter) loop was co-residency-starved at N-tile 128.
// ---------------------------------------------------------------------------
#define GEMM_CORE(A_, W_, K_)                                                  \
    __shared__ bf16 As[128][64];                                               \
    __shared__ bf16 Bs[64][64];                                                \
    const int tid  = threadIdx.x;                                              \
    const int wave = tid >> 6;                                                 \
    const int lane = tid & 63;                                                 \
    const int wm   = (wave >> 1) * 64;                                         \
    const int wn   = (wave & 1) * 32;                                          \
    const int l16  = lane & 15;                                                \
    const int quad = lane >> 4;                                                \
    const int row0 = blockIdx.x * 128;                                         \
    const int col0 = blockIdx.y * 64;                                          \
    f32x4 acc[4][2] = {};                                                      \
    for (int k0 = 0; k0 < (K_); k0 += 64) {                                    \
        _Pragma("unroll")                                                      \
        for (int it = 0; it < 6; ++it) {                                       \
            int f = it * 256 + tid;                                            \
            if (f < 1024) {                                                    \
                int r = f >> 3, pc = f & 7, lc = pc ^ (r & 7);                 \
                async_cp16(&(A_)[(size_t)(row0 + r) * (K_) + k0 + lc * 8],     \
                           &As[r][pc * 8]);                                    \
            } else {                                                           \
                int g = f - 1024;                                              \
                int r = g >> 3, pc = g & 7, lc = pc ^ (r & 7);                 \
                async_cp16(&(W_)[(size_t)(col0 + r) * (K_) + k0 + lc * 8],     \
                           &Bs[r][pc * 8]);                                    \
            }                                                                  \
        }                                                                      \
        __syncthreads();                                                       \
        _Pragma("unroll")                                                      \
        for (int ks = 0; ks < 2; ++ks) {                                       \
            bf16x8 af[4], bfr[2];                                              \
            _Pragma("unroll")                                                  \
            for (int i = 0; i < 4; ++i) {                                      \
                int ra = wm + i * 16 + l16;                                    \
                af[i] = *(const bf16x8*)(&As[ra][((ks * 4 + quad) ^ (ra & 7)) * 8]); \
            }                                                                  \
            _Pragma("unroll")                                                  \
            for (int i = 0; i < 2; ++i) {                                      \
                int rb = wn + i * 16 + l16;                                    \
                bfr[i] = *(const bf16x8*)(&Bs[rb][((ks * 4 + quad) ^ (rb & 7)) * 8]); \
            }                                                                  \
            _Pragma("unroll")                                                  \
            for (int mi = 0; mi < 4; ++mi)                                     \
                _Pragma("unroll")                                              \
                for (int ni = 0; ni < 2; ++ni)                                 \
                    acc[mi][ni] = __builtin_amdgcn_mfma_f32_16x16x32_bf16(     \
                        af[mi], bfr[ni], acc[mi][ni], 0, 0, 0);                \
        }                                                                      \
        __syncthreads();                                                       \
    }

// ---------------------------------------------------------------------------
// QKV GEMM (split epilogue): cols 0..1023 (Q,K) -> qk row-major (stride
// 1024); cols 1024..1535 (V) -> vT[b][h][d][l] transposed, packed bf16x4.
// ---------------------------------------------------------------------------
__global__ __launch_bounds__(256)
void gemm_qkv(const bf16* __restrict__ A, const bf16* __restrict__ W,
              const bf16* __restrict__ bias,
              bf16* __restrict__ qk, bf16* __restrict__ vT)
{
    GEMM_CORE(A, W, DIM_)

    if (col0 < 1024) {
        #pragma unroll
        for (int ni = 0; ni < 2; ++ni) {
            int n = col0 + wn + ni * 16 + l16;
            float bv = (float)bias[n];
            #pragma unroll
            for (int mi = 0; mi < 4; ++mi) {
                int mrow = row0 + wm + mi * 16 + quad * 4;
                #pragma unroll
                for (int r = 0; r < 4; ++r)
                    qk[(size_t)(mrow + r) * QKS_ + n] = (bf16)(acc[mi][ni][r] + bv);
            }
        }
    } else {
        #pragma unroll
        for (int ni = 0; ni < 2; ++ni) {
            int nf = col0 + wn + ni * 16 + l16;     // 1024..1535
            float bv = (float)bias[nf];
            int hd = nf - 1024;                     // h*64 + d
            #pragma unroll
            for (int mi = 0; mi < 4; ++mi) {
                int m = row0 + wm + mi * 16 + quad * 4;
                int b = m >> 12;
                int l = m & (L_ - 1);
                bf16x4 v4;
                #pragma unroll
                for (int r = 0; r < 4; ++r) v4[r] = (bf16)(acc[mi][ni][r] + bv);
                *(bf16x4*)(vT + ((size_t)(b * DIM_ + hd)) * L_ + l) = v4;
            }
        }
    }
}

// ---------------------------------------------------------------------------
// Proj GEMM: C[M,512] = A @ W^T + bias, fp32 out.
// ---------------------------------------------------------------------------
__global__ __launch_bounds__(256)
void gemm_proj(const bf16* __restrict__ A, const bf16* __restrict__ W,
               const bf16* __restrict__ bias, float* __restrict__ C)
{
    GEMM_CORE(A, W, DIM_)

    #pragma unroll
    for (int ni = 0; ni < 2; ++ni) {
        int n = col0 + wn + ni * 16 + l16;
        float bv = (float)bias[n];
        #pragma unroll
        for (int mi = 0; mi < 4; ++mi) {
            int mrow = row0 + wm + mi * 16 + quad * 4;
            #pragma unroll
            for (int r = 0; r < 4; ++r)
                C[(size_t)(mrow + r) * DIM_ + n] = acc[mi][ni][r] + bv;
        }
    }
}

// ---------------------------------------------------------------------------
// MFMA neighborhood attention, vT version (R8, passing, unchanged).
// ---------------------------------------------------------------------------
__global__ __launch_bounds__(256)
void na1d_attn_mfma(const bf16* __restrict__ qk, const bf16* __restrict__ vT,
                    bf16* __restrict__ att)
{
    __shared__ bf16 Klds[96 * 64];
    __shared__ bf16 Plds[4][16][72];

    const int tid  = threadIdx.x;
    const int wave = tid >> 6;
    const int lane = tid & 63;
    const int l16  = lane & 15;
    const int quad = lane >> 4;

    const int xcd  = blockIdx.x & 7;
    const int s    = blockIdx.x >> 3;
    const int jj   = s & 3;
    const int half = (s >> 2) & 1;
    const int h    = (s >> 3) & 7;
    const int b    = s >> 6;
    const int p    = jj * 8 + xcd;
    const int Q0   = p * 128 + half * 64;

    const size_t rowbase = (size_t)b * L_;

    #pragma unroll
    for (int i = 0; i < 3; ++i) {
        int ck = i * 256 + tid;
        int r  = ck >> 3;
        int pc = ck & 7;
        int lc = pc ^ (r & 7);
        int g  = Q0 - 16 + r;
        g = g < 0 ? 0 : (g > L_ - 1 ? L_ - 1 : g);
        async_cp16(qk + (rowbase + g) * QKS_ + DIM_ + h * HDIM_ + lc * 8,
                   Klds + (size_t)ck * 8);
    }

    const int q0w = Q0 + wave * 16;
    const bf16* qptr = qk + (rowbase + q0w + l16) * QKS_ + h * HDIM_ + quad * 8;
    bf16x8 qf0 = *(const bf16x8*)(qptr);
    bf16x8 qf1 = *(const bf16x8*)(qptr + 32);

    int k_base = q0w - 16;
    if (k_base > L_ - 48) k_base = L_ - 48;
    if (k_base < 0) k_base = 0;
    const int rel = k_base - (Q0 - 16);

    __syncthreads();

    f32x4 sacc[3] = {};
    #pragma unroll
    for (int t = 0; t < 3; ++t) {
        int r = rel + t * 16 + l16;
        bf16x8 kf0 = *(const bf16x8*)(Klds + r * 64 + ((quad ^ (r & 7)) * 8));
        bf16x8 kf1 = *(const bf16x8*)(Klds + r * 64 + (((4 + quad) ^ (r & 7)) * 8));
        sacc[t] = __builtin_amdgcn_mfma_f32_16x16x32_bf16(qf0, kf0, sacc[t], 0, 0, 0);
        sacc[t] = __builtin_amdgcn_mfma_f32_16x16x32_bf16(qf1, kf1, sacc[t], 0, 0, 0);
    }

    int offr[4];
    #pragma unroll
    for (int r = 0; r < 4; ++r) {
        int lq = q0w + quad * 4 + r;
        int st = lq - KS_ / 2;
        if (st < 0) st = 0;
        if (st > L_ - KS_) st = L_ - KS_;
        offr[r] = st - k_base;
    }
    float sv[3][4];
    #pragma unroll
    for (int t = 0; t < 3; ++t) {
        int j = t * 16 + l16;
        #pragma unroll
        for (int r = 0; r < 4; ++r) {
            float xv = sacc[t][r] * 0.125f;
            sv[t][r] = (j >= offr[r] && j <= offr[r] + 32) ? xv : -1e30f;
        }
    }

    float mr[4], sum[4];
    #pragma unroll
    for (int r = 0; r < 4; ++r)
        mr[r] = fmaxf(fmaxf(sv[0][r], sv[1][r]), sv[2][r]);
    #pragma unroll
    for (int o = 1; o < 16; o <<= 1)
        #pragma unroll
        for (int r = 0; r < 4; ++r)
            mr[r] = fmaxf(mr[r], __shfl_xor(mr[r], o, 64));
    #pragma unroll
    for (int t = 0; t < 3; ++t)
        #pragma unroll
        for (int r = 0; r < 4; ++r)
            sv[t][r] = __expf(sv[t][r] - mr[r]);
    #pragma unroll
    for (int r = 0; r < 4; ++r)
        sum[r] = sv[0][r] + sv[1][r] + sv[2][r];
    #pragma unroll
    for (int o = 1; o < 16; o <<= 1)
        #pragma unroll
        for (int r = 0; r < 4; ++r)
            sum[r] += __shfl_xor(sum[r], o, 64);
    #pragma unroll
    for (int r = 0; r < 4; ++r) {
        float inv = 1.0f / sum[r];
        #pragma unroll
        for (int t = 0; t < 3; ++t) sv[t][r] *= inv;
    }

    bf16* P = &Plds[wave][0][0];
    {
        int rr = lane >> 2;
        int c0 = 48 + (lane & 3) * 4;
        *(bf16x4*)(&P[rr * 72 + c0]) = (bf16x4){(bf16)0.f, (bf16)0.f, (bf16)0.f, (bf16)0.f};
    }
    #pragma unroll
    for (int t = 0; t < 3; ++t)
        #pragma unroll
        for (int r = 0; r < 4; ++r)
            P[(quad * 4 + r) * 72 + t * 16 + l16] = (bf16)sv[t][r];
    __syncthreads();

    bf16x8 pf0 = *(const bf16x8*)(&P[l16 * 72 + quad * 8]);
    bf16x8 pf1 = *(const bf16x8*)(&P[l16 * 72 + 32 + quad * 8]);

    const bf16* vbase = vT + (size_t)(b * DIM_ + h * HDIM_) * L_;
    int c1 = k_base + quad * 8;
    int c2 = k_base + 32 + quad * 8;
    if (c2 > L_ - 8) c2 = L_ - 8;
    f32x4 o[4] = {};
    #pragma unroll
    for (int t = 0; t < 4; ++t) {
        const bf16* vrow = vbase + (size_t)(t * 16 + l16) * L_;
        bf16x8 vf0 = *(const bf16x8*)(vrow + c1);
        bf16x8 vf1 = *(const bf16x8*)(vrow + c2);
        o[t] = __builtin_amdgcn_mfma_f32_16x16x32_bf16(pf0, vf0, o[t], 0, 0, 0);
        o[t] = __builtin_amdgcn_mfma_f32_16x16x32_bf16(pf1, vf1, o[t], 0, 0, 0);
    }

    bf16* orow = att + (rowbase + q0w) * DIM_ + h * HDIM_;
    #pragma unroll
    for (int t = 0; t < 4; ++t)
        #pragma unroll
        for (int r = 0; r < 4; ++r)
            orow[(size_t)(quad * 4 + r) * DIM_ + t * 16 + l16] = (bf16)o[t][r];
}

extern "C" void kernel_launch(void* const* d_in, const int* in_sizes, int n_in,
                              void* d_out, int out_size, void* d_ws, size_t ws_size,
                              hipStream_t stream) {
    const int n_x  = B_ * L_ * DIM_;       // 4194304
    const int n_wq = 3 * DIM_ * DIM_;      // 786432
    const int n_bq = 3 * DIM_;             // 1536
    const int n_wp = DIM_ * DIM_;          // 262144
    const int n_bp = DIM_;                 // 512

    char* ws = (char*)d_ws;
    bf16* xb  = (bf16*)ws;
    bf16* wqb = xb  + n_x;
    bf16* bqb = wqb + n_wq;
    bf16* wpb = bqb + n_bq;
    bf16* bpb = wpb + n_wp;
    bf16* qk  = bpb + n_bp;                          // 8192 x 1024
    bf16* vT  = qk  + (size_t)8192 * 1024;           // (b, h*d, l)
    bf16* att = vT  + (size_t)B_ * DIM_ * L_;        // 8192 x 512

    float* out = (float*)d_out;
    const int M = B_ * L_;  // 8192

    cvt_all<<<2562, 256, 0, stream>>>(
        (const float*)d_in[0], (const float*)d_in[1], (const float*)d_in[2],
        (const float*)d_in[3], (const float*)d_in[4],
        xb, wqb, bqb, wpb, bpb);

    gemm_qkv<<<dim3(M / 128, (3 * DIM_) / 64), 256, 0, stream>>>(
        xb, wqb, bqb, qk, vT);

    na1d_attn_mfma<<<dim3((B_ * HEADS_ * L_) / 64), 256, 0, stream>>>(qk, vT, att);

    gemm_proj<<<dim3(M / 128, DIM_ / 64), 256, 0, stream>>>(
        att, wpb, bpb, out);
}